// Round 8
// baseline (6320.452 us; speedup 1.0000x reference)
//
#include <hip/hip_runtime.h>

// ---------------------------------------------------------------------------
// MonarchMixerLayer fp32, B=32, N=D=1024, s=32.
//   p1 (per b, 32-wide d-tile, 2 passes of 16): monarch(m1) -> relu(nk*) ->
//       monarch(m2) -> xt
//   p2 (per b, 16-row n-tile): monarch(m3, dk-fused) -> monarch(m4) -> +xt -> LN
//
// Round-8 = round-7 resubmitted verbatim (round 7 never ran: GPU acquisition
// timeout). DOUBLE-BUFFERED monarch (stage A: bufA->bufB, stage B:
// bufB->bufA). This removes the in-place write race that forced M[32]+acc[32]
// preloads (>=64 floats live) -- the structural cause of the scratch spill
// that rounds 3-6 could not fix via allocator knobs (VGPR_Count pinned at 64,
// p2 WRITE 614MB vs 128MB ideal). Both stages stream operands 4-at-a-time
// and each thread computes 16 outputs (h-split): live set ~48 regs < 64.
// 2 barriers/monarch (down from 3).
//
// Monarch math (validated rounds 2-6):
//   out[u*32+r] = sum_m R[r][u][m] * sum_k L[m][r][k] * in[k*32+m]
// Stage A thread (p,l,h): T[c]=sum_k L[p][c][k]*V[k*32+p], c=h*16+i -> bufB.
// Stage B thread (r,l,h): OUT[u]=sum_m R[r][u][m]*T[r*32+m], u=h*16+i -> bufA.
// ---------------------------------------------------------------------------

// [1024][16] tile; float4-safe XOR swizzle (offset multiple of 4).
// Bank audit: monarch reads/writes 2-way (free); epilogue reads 8-way on only
// 16 ops/thread (negligible); transpose-load ~16-way one-time (accepted).
__device__ __forceinline__ int cellA(int n, int l) {
  return (n << 4) + (l ^ (((n >> 1) ^ (n >> 5)) & 12));
}

// One monarch over 16 resident vectors, double-buffered: result lands in src.
// l = vector 0..15, p = block-row 0..31, h = output half 0..1.
// FUSE_DK: v = relu(v * dk[n]) on stage-B output (dk 4KB, L1-resident).
template <bool FUSE_DK>
__device__ __forceinline__ void monarchDB(float* src, float* dst,
                                          const float* __restrict__ L,
                                          const float* __restrict__ R,
                                          const float* __restrict__ dk,
                                          int l, int p, int h) {
  {  // ---- Stage A: read src, write dst. T[c] = sum_k L[p][c][k]*X[k].
    const float* Wp = L + (p << 10) + (h << 9);  // rows c = h*16 + i
    float acc[16];
#pragma unroll
    for (int i = 0; i < 16; ++i) acc[i] = 0.f;
#pragma unroll
    for (int kb = 0; kb < 8; ++kb) {
      const int k0 = kb << 2;
      const float x0 = src[cellA(((k0 + 0) << 5) + p, l)];
      const float x1 = src[cellA(((k0 + 1) << 5) + p, l)];
      const float x2 = src[cellA(((k0 + 2) << 5) + p, l)];
      const float x3 = src[cellA(((k0 + 3) << 5) + p, l)];
#pragma unroll
      for (int cq = 0; cq < 4; ++cq) {  // 4 independent loads + FMA chains
        const float* wr = Wp + (cq << 7) + k0;  // (cq*4)<<5 == cq<<7
        float4 w0 = *(const float4*)(wr);
        float4 w1 = *(const float4*)(wr + 32);
        float4 w2 = *(const float4*)(wr + 64);
        float4 w3 = *(const float4*)(wr + 96);
        const int c4 = cq << 2;
        acc[c4 + 0] = fmaf(w0.x, x0, fmaf(w0.y, x1, fmaf(w0.z, x2, fmaf(w0.w, x3, acc[c4 + 0]))));
        acc[c4 + 1] = fmaf(w1.x, x0, fmaf(w1.y, x1, fmaf(w1.z, x2, fmaf(w1.w, x3, acc[c4 + 1]))));
        acc[c4 + 2] = fmaf(w2.x, x0, fmaf(w2.y, x1, fmaf(w2.z, x2, fmaf(w2.w, x3, acc[c4 + 2]))));
        acc[c4 + 3] = fmaf(w3.x, x0, fmaf(w3.y, x1, fmaf(w3.z, x2, fmaf(w3.w, x3, acc[c4 + 3]))));
      }
    }
#pragma unroll
    for (int i = 0; i < 16; ++i)
      dst[cellA((((h << 4) + i) << 5) + p, l)] = acc[i];
  }
  __syncthreads();  // stage-A writes visible; src free for stage-B writes
  {  // ---- Stage B: read dst, write src. OUT[u] = sum_m R[p][u][m]*T[m].
    const float* Wp = R + (p << 10) + (h << 9);
    float acc[16];
#pragma unroll
    for (int i = 0; i < 16; ++i) acc[i] = 0.f;
#pragma unroll
    for (int kb = 0; kb < 8; ++kb) {
      const int k0 = kb << 2;
      const float m0 = dst[cellA((p << 5) + k0 + 0, l)];
      const float m1 = dst[cellA((p << 5) + k0 + 1, l)];
      const float m2 = dst[cellA((p << 5) + k0 + 2, l)];
      const float m3 = dst[cellA((p << 5) + k0 + 3, l)];
#pragma unroll
      for (int cq = 0; cq < 4; ++cq) {
        const float* wr = Wp + (cq << 7) + k0;
        float4 w0 = *(const float4*)(wr);
        float4 w1 = *(const float4*)(wr + 32);
        float4 w2 = *(const float4*)(wr + 64);
        float4 w3 = *(const float4*)(wr + 96);
        const int c4 = cq << 2;
        acc[c4 + 0] = fmaf(w0.x, m0, fmaf(w0.y, m1, fmaf(w0.z, m2, fmaf(w0.w, m3, acc[c4 + 0]))));
        acc[c4 + 1] = fmaf(w1.x, m0, fmaf(w1.y, m1, fmaf(w1.z, m2, fmaf(w1.w, m3, acc[c4 + 1]))));
        acc[c4 + 2] = fmaf(w2.x, m0, fmaf(w2.y, m1, fmaf(w2.z, m2, fmaf(w2.w, m3, acc[c4 + 2]))));
        acc[c4 + 3] = fmaf(w3.x, m0, fmaf(w3.y, m1, fmaf(w3.z, m2, fmaf(w3.w, m3, acc[c4 + 3]))));
      }
    }
#pragma unroll
    for (int i = 0; i < 16; ++i) {
      const int n = (((h << 4) + i) << 5) + p;
      float v = acc[i];
      if (FUSE_DK) {
        float a = v * dk[n];
        v = a > 0.f ? a : 0.f;
      }
      src[cellA(n, l)] = v;
    }
  }
  __syncthreads();  // result in src, all synced
}

// Phase 1: sequence mixing. grid (32 d32-tiles, 32 b), block 1024, 2x64KB LDS.
// Two 16-wide passes per block keep x/xt global I/O on full 128B lines
// (pass 2's other 64B half comes from L1/L2 of the same CU).
__global__ __launch_bounds__(1024) void p1_kernel(
    const float* __restrict__ x, const float* __restrict__ m1L,
    const float* __restrict__ m1R, const float* __restrict__ m2L,
    const float* __restrict__ m2R, const float* __restrict__ nk,
    float* __restrict__ xt_out) {
  __shared__ float bufA[1024 * 16];
  __shared__ float bufB[1024 * 16];
  const int b = blockIdx.y, d32 = blockIdx.x << 5;
  const int tid = (int)threadIdx.x;
  const int l = tid & 15, p = (tid >> 4) & 31, h = tid >> 9;

  for (int pass = 0; pass < 2; ++pass) {
    const int d0 = d32 + (pass << 4);
    __syncthreads();  // guard bufA overwrite vs previous pass's store reads
    {  // load x[b, n, d0..d0+15]: 4 float4/thread
      const int g4 = tid & 3, nn = tid >> 2, l4 = g4 << 2;
      const float* xb = x + ((size_t)b << 20) + d0 + l4;
#pragma unroll
      for (int j = 0; j < 4; ++j) {
        const int n = (j << 8) + nn;
        float4 v = *(const float4*)&xb[(size_t)n << 10];
        *(float4*)&bufA[cellA(n, l4)] = v;  // swizzle 4-aligned
      }
    }
    __syncthreads();
    monarchDB<false>(bufA, bufB, m1L, m1R, nullptr, l, p, h);
    {  // relu(nk[d0+le][n] * v): thread-local cells; nk reads 256B/wave
      const int q6 = tid & 63, le = tid >> 6;
      const float* nkr = nk + ((size_t)(d0 + le) << 10);
#pragma unroll
      for (int j = 0; j < 16; ++j) {
        const int n = (j << 6) + q6;
        const int a = cellA(n, le);
        float v = bufA[a] * nkr[n];
        bufA[a] = v > 0.f ? v : 0.f;
      }
    }
    __syncthreads();
    monarchDB<false>(bufA, bufB, m2L, m2R, nullptr, l, p, h);
    {  // store x_tilde[b, n, d0..d0+15]
      const int g4 = tid & 3, nn = tid >> 2, l4 = g4 << 2;
      float* ob = xt_out + ((size_t)b << 20) + d0 + l4;
#pragma unroll
      for (int j = 0; j < 4; ++j) {
        const int n = (j << 8) + nn;
        float4 v = *(const float4*)&bufA[cellA(n, l4)];
        *(float4*)&ob[(size_t)n << 10] = v;
      }
    }
  }
}

// Phase 2: dim mixing + residual + LN. grid (64 n-tiles, 32 b), block 1024,
// 2x64KB LDS. In-place on d_out: each n-cell is read (resid) and written
// (store) by the same owning thread, reads first; rows block-exclusive.
__global__ __launch_bounds__(1024) void p2_kernel(
    const float* xt, const float* __restrict__ m3L,
    const float* __restrict__ m3R, const float* __restrict__ m4L,
    const float* __restrict__ m4R, const float* __restrict__ dk,
    const float* __restrict__ gamma, const float* __restrict__ beta,
    float* out) {
  __shared__ float bufA[1024 * 16];
  __shared__ float bufB[1024 * 16];
  const int b = blockIdx.y, n0 = blockIdx.x << 4;
  const int tid = (int)threadIdx.x;
  const int l = tid & 15, p = (tid >> 4) & 31, h = tid >> 9;
  const float* xrows = xt + ((((size_t)b << 10) + n0) << 10);

  {  // transpose-load 16 rows: global 1KB contiguous/wave-instr
    const int q6 = tid & 63, lr = tid >> 6;
    const float* xr = xrows + ((size_t)lr << 10);
#pragma unroll
    for (int j = 0; j < 4; ++j) {
      const int d = (j << 8) + (q6 << 2);
      float4 v = *(const float4*)&xr[d];
      bufA[cellA(d + 0, lr)] = v.x;
      bufA[cellA(d + 1, lr)] = v.y;
      bufA[cellA(d + 2, lr)] = v.z;
      bufA[cellA(d + 3, lr)] = v.w;
    }
  }
  __syncthreads();
  monarchDB<true>(bufA, bufB, m3L, m3R, dk, l, p, h);   // dk*relu fused
  monarchDB<false>(bufA, bufB, m4L, m4R, nullptr, l, p, h);
  {  // h = y + xt (256B/wave resid re-read); two-pass LN; 256B/wave store
    const int q6 = tid & 63, lr = tid >> 6;
    const float* xr = xrows + ((size_t)lr << 10);
    float hb[16];
    float s = 0.f;
#pragma unroll
    for (int j = 0; j < 16; ++j) {
      const int n = (j << 6) + q6;
      float hv = bufA[cellA(n, lr)] + xr[n];
      hb[j] = hv;
      s += hv;
    }
#pragma unroll
    for (int m = 1; m <= 32; m <<= 1) s += __shfl_xor(s, m);
    const float mu = s * (1.f / 1024.f);
    float vs = 0.f;
#pragma unroll
    for (int j = 0; j < 16; ++j) {
      float d = hb[j] - mu;
      vs = fmaf(d, d, vs);
    }
#pragma unroll
    for (int m = 1; m <= 32; m <<= 1) vs += __shfl_xor(vs, m);
    const float rs = rsqrtf(vs * (1.f / 1024.f) + 1e-5f);
    float* orow = out + ((((size_t)b << 10) + n0 + lr) << 10);
#pragma unroll
    for (int j = 0; j < 16; ++j) {
      const int n = (j << 6) + q6;
      orow[n] = (hb[j] - mu) * rs * gamma[n] + beta[n];
    }
  }
}

extern "C" void kernel_launch(void* const* d_in, const int* in_sizes, int n_in,
                              void* d_out, int out_size, void* d_ws, size_t ws_size,
                              hipStream_t stream) {
  (void)in_sizes; (void)n_in; (void)out_size; (void)d_ws; (void)ws_size;
  const float* x   = (const float*)d_in[0];
  const float* m1L = (const float*)d_in[1];
  const float* m1R = (const float*)d_in[2];
  const float* m2L = (const float*)d_in[3];
  const float* m2R = (const float*)d_in[4];
  const float* m3L = (const float*)d_in[5];
  const float* m3R = (const float*)d_in[6];
  const float* m4L = (const float*)d_in[7];
  const float* m4R = (const float*)d_in[8];
  const float* nk  = (const float*)d_in[9];
  const float* dk  = (const float*)d_in[10];
  const float* gam = (const float*)d_in[11];
  const float* bet = (const float*)d_in[12];
  float* out = (float*)d_out;

  hipLaunchKernelGGL(p1_kernel, dim3(32, 32), dim3(1024), 0, stream,
                     x, m1L, m1R, m2L, m2R, nk, out);
  hipLaunchKernelGGL(p2_kernel, dim3(64, 32), dim3(1024), 0, stream,
                     out, m3L, m3R, m4L, m4R, dk, gam, bet, out);
}